// Round 11
// baseline (433.759 us; speedup 1.0000x reference)
//
#include <hip/hip_runtime.h>
#include <cstdint>
#include <cstddef>

#define Nn 2048
#define FIN 256
#define EFEAT 32
#define HID 64
#define NH 4
#define NL 3
#define LRELU_A 0.2f

typedef _Float16 h4 __attribute__((ext_vector_type(4)));
typedef float f2 __attribute__((ext_vector_type(2)));
typedef float f4 __attribute__((ext_vector_type(4)));

#define NEGH ((_Float16)(-60000.0f))

// ================= ABLATION 1: pure coalesced e read stream, x8, no stores =================
__global__ __launch_bounds__(256) void k_esc_loads(const float* __restrict__ e,
                                                   const int* __restrict__ adj) {
  size_t base = (size_t)blockIdx.x * 256;
  int t = threadIdx.x;
  const f4* src = (const f4*)(e + base * EFEAT);
  int aj = adj[base + t];
  asm volatile("" :: "v"(aj));
#pragma clang loop unroll(disable)
  for (int rep = 0; rep < 8; ++rep) {
    f4 v[8];
#pragma unroll
    for (int k = 0; k < 8; ++k) v[k] = src[t + 256 * k];
#pragma unroll
    for (int k = 0; k < 8; ++k)
      asm volatile("" :: "v"(v[k][0]), "v"(v[k][1]), "v"(v[k][2]), "v"(v[k][3]));
    asm volatile("" ::: "memory");
  }
}

// ================= ABLATION 2: pure es store pattern, x8, no e reads =================
__global__ __launch_bounds__(256) void k_esc_stores(const int* __restrict__ adj,
                                                    _Float16* __restrict__ es) {
  size_t idx = (size_t)blockIdx.x * 256 + threadIdx.x;
  int m = (int)(idx & (Nn - 1));
  int n = (int)(idx >> 11);
  int mt = m >> 6, ml = m & 63;
  const size_t cstride = (size_t)32 * Nn * 64;
  size_t sbase = ((size_t)mt * Nn + n) * 64 + (size_t)ml;
  int aj = adj[idx];
#pragma clang loop unroll(disable)
  for (int rep = 0; rep < 8; ++rep) {
#pragma clang loop unroll(disable)
    for (int c = 0; c < NL * NH; ++c) {
      es[(size_t)c * cstride + sbase] = aj ? (_Float16)(0.123f) : NEGH;
    }
    asm volatile("" ::: "memory");
  }
}

// ================= real pipeline (best-known: R5 masked escore + merged h0||coef) =================
__device__ __forceinline__ void coef_body(int lh, int t, const float* __restrict__ W,
                                          const float* __restrict__ We, const float* __restrict__ a,
                                          float* __restrict__ coef, float* tl) {
  const float* Wb = W + (size_t)lh * FIN * HID;
  const float* ab = a + (size_t)lh * (3 * HID) + 2 * HID;
  float acc = 0.f;
#pragma unroll 8
  for (int o = 0; o < HID; ++o) acc = fmaf(Wb[(size_t)t * HID + o], ab[o], acc);
  tl[t] = acc;
  __syncthreads();
  if (t < EFEAT) {
    const float* Web = We + ((size_t)lh * EFEAT + t) * FIN;
    float c = 0.f;
    for (int i = 0; i < FIN; ++i) c = fmaf(Web[i], tl[i], c);
    coef[lh * EFEAT + t] = c;
  }
}

__device__ __forceinline__ void h_body(int n0, int t, const float* __restrict__ x,
                                       const float* __restrict__ W, const float* __restrict__ a,
                                       int layer, _Float16* __restrict__ hT,
                                       float* __restrict__ s1, float* __restrict__ s2) {
  int h = t >> 6, o = t & 63;
  const float* Wb = W + ((size_t)(layer * NH + h) * FIN) * HID + o;
  const float* xb = x + (size_t)n0 * FIN;
  float acc[4] = {};
  for (int i0 = 0; i0 < FIN; i0 += 4) {
    float w0 = Wb[(size_t)(i0 + 0) * HID];
    float w1 = Wb[(size_t)(i0 + 1) * HID];
    float w2 = Wb[(size_t)(i0 + 2) * HID];
    float w3 = Wb[(size_t)(i0 + 3) * HID];
#pragma unroll
    for (int j = 0; j < 4; ++j) {
      float4 xv = *(const float4*)(xb + (size_t)j * FIN + i0);   // uniform -> SGPR
      acc[j] = fmaf(xv.x, w0, acc[j]);
      acc[j] = fmaf(xv.y, w1, acc[j]);
      acc[j] = fmaf(xv.z, w2, acc[j]);
      acc[j] = fmaf(xv.w, w3, acc[j]);
    }
  }
  const float* ab = a + (size_t)(layer * NH + h) * (3 * HID);
  float a1v = ab[o], a2v = ab[HID + o];
#pragma unroll
  for (int j = 0; j < 4; ++j) {
    float r1 = acc[j] * a1v, r2 = acc[j] * a2v;
#pragma unroll
    for (int d = 1; d < 64; d <<= 1) {
      r1 += __shfl_xor(r1, d, 64);
      r2 += __shfl_xor(r2, d, 64);
    }
    if (o == 0) { s1[h * Nn + n0 + j] = r1; s2[h * Nn + n0 + j] = r2; }
  }
  int mt = n0 >> 6, ml = n0 & 63;
  h4 hv;
#pragma unroll
  for (int j = 0; j < 4; ++j) hv[j] = (_Float16)acc[j];
  *(h4*)(hT + (((size_t)h * 32 + mt) * 64 + o) * 64 + ml) = hv;
}

__global__ __launch_bounds__(256) void k_h0_coef(
    const float* __restrict__ x, const float* __restrict__ W, const float* __restrict__ We,
    const float* __restrict__ a, _Float16* __restrict__ hT,
    float* __restrict__ s1, float* __restrict__ s2, float* __restrict__ coef) {
  __shared__ float tl[FIN];
  if (blockIdx.x < Nn / 4) {
    h_body(blockIdx.x * 4, threadIdx.x, x, W, a, 0, hT, s1, s2);
  } else {
    coef_body(blockIdx.x - Nn / 4, threadIdx.x, W, We, a, coef, tl);
  }
}

__global__ __launch_bounds__(256) void k_h(
    const float* __restrict__ x, const float* __restrict__ W,
    const float* __restrict__ a, int layer,
    _Float16* __restrict__ hT, float* __restrict__ s1, float* __restrict__ s2) {
  h_body(blockIdx.x * 4, threadIdx.x, x, W, a, layer, hT, s1, s2);
}

// R5 masked-gather escore (measured 133 us) — the real producer
template <int C>
__global__ __launch_bounds__(256) void k_escore(
    const float* __restrict__ e, const int* __restrict__ adj,
    const float* __restrict__ coef, _Float16* __restrict__ es) {
  size_t idx = (size_t)blockIdx.x * 256 + threadIdx.x;   // n*Nn + m
  int m = (int)(idx & (Nn - 1));
  int n = (int)(idx >> 11);
  int mt = m >> 6, ml = m & 63;
  const size_t cstride = (size_t)32 * Nn * 64;
  size_t sbase = ((size_t)mt * Nn + n) * 64 + (size_t)ml;
  int aj = adj[idx];
  float evv[EFEAT] = {};
  if (aj != 0) {
    const float4* ep = (const float4*)(e + idx * EFEAT);
#pragma unroll
    for (int g = 0; g < 8; ++g) {
      float4 v = ep[g];
      evv[g * 4 + 0] = v.x; evv[g * 4 + 1] = v.y; evv[g * 4 + 2] = v.z; evv[g * 4 + 3] = v.w;
    }
  }
#pragma clang loop unroll(disable)
  for (int c = 0; c < C; ++c) {
    const float* cf = coef + c * EFEAT;   // wave-uniform -> s_load
    float acc = 0.f;
#pragma unroll
    for (int f = 0; f < EFEAT; ++f) acc = fmaf(evv[f], cf[f], acc);
    es[(size_t)c * cstride + sbase] = aj ? (_Float16)acc : NEGH;
  }
}

__global__ __launch_bounds__(512, 2) void k_attn(
    const _Float16* __restrict__ es, const _Float16* __restrict__ hT,
    const float* __restrict__ s1, const float* __restrict__ s2,
    float* __restrict__ hp, float* __restrict__ xn, int layer, int last) {
  int h = blockIdx.x;
  int n0 = blockIdx.y * 16;
  int t = threadIdx.x;
  int w = t >> 6;
  int l = t & 63;
  int col = l & 15, grp = l >> 4;
  int n = n0 + col;
  float s1v = s1[h * Nn + n];
  const _Float16* esb = es + (size_t)(layer * NH + h) * ((size_t)32 * Nn * 64);
  const _Float16* hTb = hT + (size_t)h * ((size_t)32 * 64 * 64);
  const float* s2b = s2 + h * Nn;

  h4 sc16[16];
  float pmax = -3.0e38f;
#pragma unroll
  for (int c16 = 0; c16 < 16; ++c16) {
    int m0 = w * 256 + c16 * 16;
    int mt = m0 >> 6;
    int ml0 = (m0 & 63) + grp * 4;
    h4 ev = *(const h4*)(esb + ((size_t)mt * Nn + n) * 64 + ml0);
    float4 sv = *(const float4*)(s2b + m0 + grp * 4);
    float sc0 = s1v + sv.x + (float)ev[0]; sc0 = fmaxf(sc0, LRELU_A * sc0);
    float sc1 = s1v + sv.y + (float)ev[1]; sc1 = fmaxf(sc1, LRELU_A * sc1);
    float sc2 = s1v + sv.z + (float)ev[2]; sc2 = fmaxf(sc2, LRELU_A * sc2);
    float sc3 = s1v + sv.w + (float)ev[3]; sc3 = fmaxf(sc3, LRELU_A * sc3);
    h4 sch;
    sch[0] = (_Float16)sc0; sch[1] = (_Float16)sc1;
    sch[2] = (_Float16)sc2; sch[3] = (_Float16)sc3;
    sc16[c16] = sch;
    pmax = fmaxf(pmax, fmaxf(fmaxf(sc0, sc1), fmaxf(sc2, sc3)));
  }
  pmax = fmaxf(pmax, __shfl_xor(pmax, 16, 64));
  float M = fmaxf(pmax, __shfl_xor(pmax, 32, 64));

  float S = 0.f;
  f4 acc[4] = {};
#pragma unroll
  for (int c16 = 0; c16 < 16; ++c16) {
    int m0 = w * 256 + c16 * 16;
    int mt = m0 >> 6;
    int ml0 = (m0 & 63) + grp * 4;
    h4 scv = sc16[c16];
    float p0 = __expf((float)scv[0] - M);
    float p1 = __expf((float)scv[1] - M);
    float p2 = __expf((float)scv[2] - M);
    float p3 = __expf((float)scv[3] - M);
    S += p0 + p1 + p2 + p3;
    h4 pb;
    pb[0] = (_Float16)p0; pb[1] = (_Float16)p1;
    pb[2] = (_Float16)p2; pb[3] = (_Float16)p3;
    const _Float16* hp0 = hTb + ((size_t)mt * 64 + col) * 64 + ml0;
#pragma unroll
    for (int ot = 0; ot < 4; ++ot) {
      h4 af = *(const h4*)(hp0 + (size_t)ot * 16 * 64);
      acc[ot] = __builtin_amdgcn_mfma_f32_16x16x16f16(af, pb, acc[ot], 0, 0, 0);
    }
  }
  S += __shfl_xor(S, 16, 64);
  S += __shfl_xor(S, 32, 64);

  __shared__ float red[8][16][64];
  __shared__ float Mw[8][16];
  __shared__ float Sw[8][16];
  if (l < 16) { Mw[w][l] = M; Sw[w][l] = S; }
#pragma unroll
  for (int ot = 0; ot < 4; ++ot)
    *(f4*)&red[w][col][ot * 16 + grp * 4] = acc[ot];
  __syncthreads();

  if (t < 256) {
    int nl = t >> 4, o0 = (t & 15) * 4;
    float Ms = Mw[0][nl];
#pragma unroll
    for (int ww = 1; ww < 8; ++ww) Ms = fmaxf(Ms, Mw[ww][nl]);
    float Ssum = 0.f;
    f4 v = {};
#pragma unroll
    for (int ww = 0; ww < 8; ++ww) {
      float f = __expf(Mw[ww][nl] - Ms);
      Ssum = fmaf(Sw[ww][nl], f, Ssum);
      f4 r = *(const f4*)&red[ww][nl][o0];
      v += r * f;
    }
    float is = 1.0f / Ssum;
    v *= is;
    if (last) {
      *(f4*)(hp + ((size_t)h * Nn + n0 + nl) * HID + o0) = v;
    } else {
      f4 xo;
#pragma unroll
      for (int k = 0; k < 4; ++k) xo[k] = v[k] > 0.f ? v[k] : expm1f(v[k]);
      *(f4*)(xn + (size_t)(n0 + nl) * FIN + h * HID + o0) = xo;
    }
  }
}

__global__ void k_out(const float* __restrict__ hp, float* __restrict__ out) {
  int idx = blockIdx.x * 256 + threadIdx.x;   // N*64
  int n = idx >> 6, o = idx & 63;
  size_t b = (size_t)n * HID + o;
  float v = 0.25f * (hp[b] + hp[(size_t)Nn * HID + b] +
                     hp[2 * (size_t)Nn * HID + b] + hp[3 * (size_t)Nn * HID + b]);
  out[idx] = v > 0.f ? v : expm1f(v);
}

extern "C" void kernel_launch(void* const* d_in, const int* in_sizes, int n_in,
                              void* d_out, int out_size, void* d_ws, size_t ws_size,
                              hipStream_t stream) {
  const float* x_in = (const float*)d_in[0];
  const int* adj = (const int*)d_in[1];
  const float* e = (const float*)d_in[2];
  const float* We = (const float*)d_in[3];
  const float* W = (const float*)d_in[4];
  const float* a = (const float*)d_in[5];
  float* out = (float*)d_out;

  char* ws = (char*)d_ws;
  size_t off = 0;
  auto alloc = [&](size_t bytes) -> void* {
    off = (off + 255) & ~(size_t)255;
    void* p = ws + off;
    off += bytes;
    return p;
  };
  float* coef = (float*)alloc((size_t)NL * NH * EFEAT * sizeof(float));
  float* s1 = (float*)alloc((size_t)NH * Nn * sizeof(float));
  float* s2 = (float*)alloc((size_t)NH * Nn * sizeof(float));
  float* hp = (float*)alloc((size_t)NH * Nn * HID * sizeof(float));
  float* xA = (float*)alloc((size_t)Nn * FIN * sizeof(float));
  float* xB = (float*)alloc((size_t)Nn * FIN * sizeof(float));
  _Float16* hT = (_Float16*)alloc((size_t)NH * 32 * 64 * 64 * sizeof(_Float16));
  _Float16* es = (_Float16*)alloc((size_t)NL * NH * 32 * Nn * 64 * sizeof(_Float16));

  size_t total = (size_t)Nn * Nn;

  // ---- ablations (measurement only; es junk overwritten by real escore below) ----
  hipLaunchKernelGGL(k_esc_loads, dim3((unsigned)(total / 256)), dim3(256), 0, stream, e, adj);
  hipLaunchKernelGGL(k_esc_stores, dim3((unsigned)(total / 256)), dim3(256), 0, stream, adj, es);

  // ---- real pipeline ----
  hipLaunchKernelGGL(k_h0_coef, dim3(Nn / 4 + NL * NH), dim3(256), 0, stream,
                     x_in, W, We, a, hT, s1, s2, coef);
  hipLaunchKernelGGL((k_escore<NL * NH>), dim3((unsigned)(total / 256)), dim3(256), 0, stream,
                     e, adj, coef, es);
  for (int l = 0; l < NL; ++l) {
    if (l > 0) {
      const float* xcur = (l == 1) ? xA : xB;
      hipLaunchKernelGGL(k_h, dim3(Nn / 4), dim3(256), 0, stream, xcur, W, a, l, hT, s1, s2);
    }
    float* xn = (l == 0) ? xA : xB;
    hipLaunchKernelGGL(k_attn, dim3(NH, Nn / 16), dim3(512), 0, stream,
                       es, hT, s1, s2, hp, xn, l, l == NL - 1 ? 1 : 0);
  }
  hipLaunchKernelGGL(k_out, dim3(Nn * HID / 256), dim3(256), 0, stream, hp, out);
}

// Round 12
// 261.623 us; speedup vs baseline: 1.6580x; 1.6580x over previous
//
#include <hip/hip_runtime.h>
#include <cstdint>
#include <cstddef>

#define Nn 2048
#define FIN 256
#define EFEAT 32
#define HID 64
#define NH 4
#define NL 3
#define LRELU_A 0.2f

typedef _Float16 h4 __attribute__((ext_vector_type(4)));
typedef float f2 __attribute__((ext_vector_type(2)));
typedef float f4 __attribute__((ext_vector_type(4)));

#define NEGH ((_Float16)(-60000.0f))

// ---------------- device bodies ----------------
__device__ __forceinline__ void coef_body(int lh, int t, const float* __restrict__ W,
                                          const float* __restrict__ We, const float* __restrict__ a,
                                          float* __restrict__ coef, float* tl) {
  const float* Wb = W + (size_t)lh * FIN * HID;
  const float* ab = a + (size_t)lh * (3 * HID) + 2 * HID;
  float acc = 0.f;
#pragma unroll 8
  for (int o = 0; o < HID; ++o) acc = fmaf(Wb[(size_t)t * HID + o], ab[o], acc);
  tl[t] = acc;
  __syncthreads();
  if (t < EFEAT) {
    const float* Web = We + ((size_t)lh * EFEAT + t) * FIN;
    float c = 0.f;
    for (int i = 0; i < FIN; ++i) c = fmaf(Web[i], tl[i], c);
    coef[lh * EFEAT + t] = c;
  }
}

__device__ __forceinline__ void h_body(int n0, int t, const float* __restrict__ x,
                                       const float* __restrict__ W, const float* __restrict__ a,
                                       int layer, _Float16* __restrict__ hT,
                                       float* __restrict__ s1, float* __restrict__ s2) {
  int h = t >> 6, o = t & 63;
  const float* Wb = W + ((size_t)(layer * NH + h) * FIN) * HID + o;
  const float* xb = x + (size_t)n0 * FIN;
  float acc[4] = {};
  for (int i0 = 0; i0 < FIN; i0 += 4) {
    float w0 = Wb[(size_t)(i0 + 0) * HID];
    float w1 = Wb[(size_t)(i0 + 1) * HID];
    float w2 = Wb[(size_t)(i0 + 2) * HID];
    float w3 = Wb[(size_t)(i0 + 3) * HID];
#pragma unroll
    for (int j = 0; j < 4; ++j) {
      float4 xv = *(const float4*)(xb + (size_t)j * FIN + i0);   // uniform -> SGPR
      acc[j] = fmaf(xv.x, w0, acc[j]);
      acc[j] = fmaf(xv.y, w1, acc[j]);
      acc[j] = fmaf(xv.z, w2, acc[j]);
      acc[j] = fmaf(xv.w, w3, acc[j]);
    }
  }
  const float* ab = a + (size_t)(layer * NH + h) * (3 * HID);
  float a1v = ab[o], a2v = ab[HID + o];
#pragma unroll
  for (int j = 0; j < 4; ++j) {
    float r1 = acc[j] * a1v, r2 = acc[j] * a2v;
#pragma unroll
    for (int d = 1; d < 64; d <<= 1) {
      r1 += __shfl_xor(r1, d, 64);
      r2 += __shfl_xor(r2, d, 64);
    }
    if (o == 0) { s1[h * Nn + n0 + j] = r1; s2[h * Nn + n0 + j] = r2; }
  }
  int mt = n0 >> 6, ml = n0 & 63;
  h4 hv;
#pragma unroll
  for (int j = 0; j < 4; ++j) hv[j] = (_Float16)acc[j];
  *(h4*)(hT + (((size_t)h * 32 + mt) * 64 + o) * 64 + ml) = hv;
}

// ---------------- merged: h(layer 0) [blocks 0..511] || coef [blocks 512..523] ----------------
__global__ __launch_bounds__(256) void k_h0_coef(
    const float* __restrict__ x, const float* __restrict__ W, const float* __restrict__ We,
    const float* __restrict__ a, _Float16* __restrict__ hT,
    float* __restrict__ s1, float* __restrict__ s2, float* __restrict__ coef) {
  __shared__ float tl[FIN];
  if (blockIdx.x < Nn / 4) {
    h_body(blockIdx.x * 4, threadIdx.x, x, W, a, 0, hT, s1, s2);
  } else {
    coef_body(blockIdx.x - Nn / 4, threadIdx.x, W, We, a, coef, tl);
  }
}

__global__ __launch_bounds__(256) void k_h(
    const float* __restrict__ x, const float* __restrict__ W,
    const float* __restrict__ a, int layer,
    _Float16* __restrict__ hT, float* __restrict__ s1, float* __restrict__ s2) {
  h_body(blockIdx.x * 4, threadIdx.x, x, W, a, layer, hT, s1, s2);
}

// ---------------- e-score: masked loads, 2 independent elements/thread (2x MLP) ----------------
// Element pair (idx, idx+256): two independent load->pk_fma->store chains per thread.
// Masked lanes skip the e fetch (exec-masked, halves bytes); select store keeps
// NEGH semantics bit-identical. es layout [c][m/64][n][m%64] unchanged.
template <int C>
__global__ __launch_bounds__(256) void k_escore(
    const float* __restrict__ e, const int* __restrict__ adj,
    const float* __restrict__ coef, _Float16* __restrict__ es) {
  int t = threadIdx.x;
  size_t base = (size_t)blockIdx.x * 512;
  size_t idx0 = base + t, idx1 = base + 256 + t;
  const size_t cstride = (size_t)32 * Nn * 64;
  int m0 = (int)(idx0 & (Nn - 1)), n0 = (int)(idx0 >> 11);
  int m1 = (int)(idx1 & (Nn - 1)), n1 = (int)(idx1 >> 11);
  size_t sb0 = (((size_t)(m0 >> 6) * Nn + n0) * 64 + (size_t)(m0 & 63));
  size_t sb1 = (((size_t)(m1 >> 6) * Nn + n1) * 64 + (size_t)(m1 & 63));
  int aj0 = adj[idx0];
  int aj1 = adj[idx1];
  f2 ev0[16], ev1[16];
#pragma unroll
  for (int g = 0; g < 16; ++g) { ev0[g] = (f2){0.f, 0.f}; ev1[g] = (f2){0.f, 0.f}; }
  if (aj0 != 0) {
    const f4* ep = (const f4*)(e + idx0 * EFEAT);
#pragma unroll
    for (int g = 0; g < 8; ++g) {
      f4 v = ep[g];
      ev0[2 * g + 0][0] = v[0]; ev0[2 * g + 0][1] = v[1];
      ev0[2 * g + 1][0] = v[2]; ev0[2 * g + 1][1] = v[3];
    }
  }
  if (aj1 != 0) {
    const f4* ep = (const f4*)(e + idx1 * EFEAT);
#pragma unroll
    for (int g = 0; g < 8; ++g) {
      f4 v = ep[g];
      ev1[2 * g + 0][0] = v[0]; ev1[2 * g + 0][1] = v[1];
      ev1[2 * g + 1][0] = v[2]; ev1[2 * g + 1][1] = v[3];
    }
  }
#pragma clang loop unroll(disable)
  for (int c = 0; c < C; ++c) {
    const f2* cf = (const f2*)(coef + c * EFEAT);   // wave-uniform -> s_load
    f2 a0 = {0.f, 0.f}, a1 = {0.f, 0.f};
#pragma unroll
    for (int f = 0; f < 16; ++f) {
      f2 cv = cf[f];
      a0 += ev0[f] * cv;   // v_pk_fma_f32, two independent chains
      a1 += ev1[f] * cv;
    }
    float r0 = a0[0] + a0[1], r1 = a1[0] + a1[1];
    es[(size_t)c * cstride + sb0] = aj0 ? (_Float16)r0 : NEGH;
    es[(size_t)c * cstride + sb1] = aj1 ? (_Float16)r1 : NEGH;
  }
}

// ---------------- attention: two-pass, h'^T = h^T @ p^T via mfma_f32_16x16x16f16 ----------------
__global__ __launch_bounds__(512, 2) void k_attn(
    const _Float16* __restrict__ es, const _Float16* __restrict__ hT,
    const float* __restrict__ s1, const float* __restrict__ s2,
    float* __restrict__ hp, float* __restrict__ xn, int layer, int last) {
  int h = blockIdx.x;
  int n0 = blockIdx.y * 16;
  int t = threadIdx.x;
  int w = t >> 6;
  int l = t & 63;
  int col = l & 15, grp = l >> 4;
  int n = n0 + col;
  float s1v = s1[h * Nn + n];
  const _Float16* esb = es + (size_t)(layer * NH + h) * ((size_t)32 * Nn * 64);
  const _Float16* hTb = hT + (size_t)h * ((size_t)32 * 64 * 64);
  const float* s2b = s2 + h * Nn;

  // ---- pass 1: scores ----
  h4 sc16[16];
  float pmax = -3.0e38f;
#pragma unroll
  for (int c16 = 0; c16 < 16; ++c16) {
    int m0 = w * 256 + c16 * 16;
    int mt = m0 >> 6;
    int ml0 = (m0 & 63) + grp * 4;
    h4 ev = *(const h4*)(esb + ((size_t)mt * Nn + n) * 64 + ml0);
    float4 sv = *(const float4*)(s2b + m0 + grp * 4);
    float sc0 = s1v + sv.x + (float)ev[0]; sc0 = fmaxf(sc0, LRELU_A * sc0);
    float sc1 = s1v + sv.y + (float)ev[1]; sc1 = fmaxf(sc1, LRELU_A * sc1);
    float sc2 = s1v + sv.z + (float)ev[2]; sc2 = fmaxf(sc2, LRELU_A * sc2);
    float sc3 = s1v + sv.w + (float)ev[3]; sc3 = fmaxf(sc3, LRELU_A * sc3);
    h4 sch;
    sch[0] = (_Float16)sc0; sch[1] = (_Float16)sc1;
    sch[2] = (_Float16)sc2; sch[3] = (_Float16)sc3;
    sc16[c16] = sch;
    pmax = fmaxf(pmax, fmaxf(fmaxf(sc0, sc1), fmaxf(sc2, sc3)));
  }
  pmax = fmaxf(pmax, __shfl_xor(pmax, 16, 64));
  float M = fmaxf(pmax, __shfl_xor(pmax, 32, 64));

  // ---- pass 2: exp + MFMA ----
  float S = 0.f;
  f4 acc[4] = {};
#pragma unroll
  for (int c16 = 0; c16 < 16; ++c16) {
    int m0 = w * 256 + c16 * 16;
    int mt = m0 >> 6;
    int ml0 = (m0 & 63) + grp * 4;
    h4 scv = sc16[c16];
    float p0 = __expf((float)scv[0] - M);
    float p1 = __expf((float)scv[1] - M);
    float p2 = __expf((float)scv[2] - M);
    float p3 = __expf((float)scv[3] - M);
    S += p0 + p1 + p2 + p3;
    h4 pb;
    pb[0] = (_Float16)p0; pb[1] = (_Float16)p1;
    pb[2] = (_Float16)p2; pb[3] = (_Float16)p3;
    const _Float16* hp0 = hTb + ((size_t)mt * 64 + col) * 64 + ml0;
#pragma unroll
    for (int ot = 0; ot < 4; ++ot) {
      h4 af = *(const h4*)(hp0 + (size_t)ot * 16 * 64);
      acc[ot] = __builtin_amdgcn_mfma_f32_16x16x16f16(af, pb, acc[ot], 0, 0, 0);
    }
  }
  S += __shfl_xor(S, 16, 64);
  S += __shfl_xor(S, 32, 64);

  __shared__ float red[8][16][64];
  __shared__ float Mw[8][16];
  __shared__ float Sw[8][16];
  if (l < 16) { Mw[w][l] = M; Sw[w][l] = S; }
#pragma unroll
  for (int ot = 0; ot < 4; ++ot)
    *(f4*)&red[w][col][ot * 16 + grp * 4] = acc[ot];
  __syncthreads();

  if (t < 256) {
    int nl = t >> 4, o0 = (t & 15) * 4;
    float Ms = Mw[0][nl];
#pragma unroll
    for (int ww = 1; ww < 8; ++ww) Ms = fmaxf(Ms, Mw[ww][nl]);
    float Ssum = 0.f;
    f4 v = {};
#pragma unroll
    for (int ww = 0; ww < 8; ++ww) {
      float f = __expf(Mw[ww][nl] - Ms);
      Ssum = fmaf(Sw[ww][nl], f, Ssum);
      f4 r = *(const f4*)&red[ww][nl][o0];
      v += r * f;
    }
    float is = 1.0f / Ssum;
    v *= is;
    if (last) {
      *(f4*)(hp + ((size_t)h * Nn + n0 + nl) * HID + o0) = v;
    } else {
      f4 xo;
#pragma unroll
      for (int k = 0; k < 4; ++k) xo[k] = v[k] > 0.f ? v[k] : expm1f(v[k]);
      *(f4*)(xn + (size_t)(n0 + nl) * FIN + h * HID + o0) = xo;
    }
  }
}

// ---------------- final output: mean over heads + elu ----------------
__global__ void k_out(const float* __restrict__ hp, float* __restrict__ out) {
  int idx = blockIdx.x * 256 + threadIdx.x;   // N*64
  int n = idx >> 6, o = idx & 63;
  size_t b = (size_t)n * HID + o;
  float v = 0.25f * (hp[b] + hp[(size_t)Nn * HID + b] +
                     hp[2 * (size_t)Nn * HID + b] + hp[3 * (size_t)Nn * HID + b]);
  out[idx] = v > 0.f ? v : expm1f(v);
}

extern "C" void kernel_launch(void* const* d_in, const int* in_sizes, int n_in,
                              void* d_out, int out_size, void* d_ws, size_t ws_size,
                              hipStream_t stream) {
  const float* x_in = (const float*)d_in[0];
  const int* adj = (const int*)d_in[1];
  const float* e = (const float*)d_in[2];
  const float* We = (const float*)d_in[3];
  const float* W = (const float*)d_in[4];
  const float* a = (const float*)d_in[5];
  float* out = (float*)d_out;

  char* ws = (char*)d_ws;
  size_t off = 0;
  auto alloc = [&](size_t bytes) -> void* {
    off = (off + 255) & ~(size_t)255;
    void* p = ws + off;
    off += bytes;
    return p;
  };
  float* coef = (float*)alloc((size_t)NL * NH * EFEAT * sizeof(float));
  float* s1 = (float*)alloc((size_t)NH * Nn * sizeof(float));
  float* s2 = (float*)alloc((size_t)NH * Nn * sizeof(float));
  float* hp = (float*)alloc((size_t)NH * Nn * HID * sizeof(float));
  float* xA = (float*)alloc((size_t)Nn * FIN * sizeof(float));
  float* xB = (float*)alloc((size_t)Nn * FIN * sizeof(float));
  _Float16* hT = (_Float16*)alloc((size_t)NH * 32 * 64 * 64 * sizeof(_Float16));
  _Float16* es = (_Float16*)alloc((size_t)NL * NH * 32 * Nn * 64 * sizeof(_Float16));

  size_t total = (size_t)Nn * Nn;

  hipLaunchKernelGGL(k_h0_coef, dim3(Nn / 4 + NL * NH), dim3(256), 0, stream,
                     x_in, W, We, a, hT, s1, s2, coef);
  hipLaunchKernelGGL((k_escore<NL * NH>), dim3((unsigned)(total / 512)), dim3(256), 0, stream,
                     e, adj, coef, es);
  for (int l = 0; l < NL; ++l) {
    if (l > 0) {
      const float* xcur = (l == 1) ? xA : xB;
      hipLaunchKernelGGL(k_h, dim3(Nn / 4), dim3(256), 0, stream, xcur, W, a, l, hT, s1, s2);
    }
    float* xn = (l == 0) ? xA : xB;
    hipLaunchKernelGGL(k_attn, dim3(NH, Nn / 16), dim3(512), 0, stream,
                       es, hT, s1, s2, hp, xn, l, l == NL - 1 ? 1 : 0);
  }
  hipLaunchKernelGGL(k_out, dim3(Nn * HID / 256), dim3(256), 0, stream, hp, out);
}